// Round 12
// baseline (281.522 us; speedup 1.0000x reference)
//
#include <hip/hip_runtime.h>
#include <stdint.h>

#define NB 4
#define CC 256
#define C16 16
#define HH 64
#define WW 64
#define NN 4096

typedef __attribute__((ext_vector_type(8))) short short8;
typedef __attribute__((ext_vector_type(4))) float floatx4;
typedef __attribute__((ext_vector_type(16))) float floatx16;

#if __has_builtin(__builtin_amdgcn_exp2f)
#define EXP2(x) __builtin_amdgcn_exp2f(x)
#else
#define EXP2(x) exp2f(x)
#endif

__device__ __forceinline__ unsigned short f2bf(float f) {
    union { float f; unsigned u; } v; v.f = f;
    unsigned r = v.u + 0x7fffu + ((v.u >> 16) & 1u);
    return (unsigned short)(r >> 16);
}
__device__ __forceinline__ float bf2f(unsigned short h) {
    union { unsigned u; float f; } v; v.u = (unsigned)h << 16;
    return v.f;
}

// Layouts:
//   xTn (K-chunked): elem (b, n, c), kq=c>>5, cc=c&31 -> ((b*8+kq)*4096 + n)*32 + cc
//   wvbn: (co, c) -> ((c>>5)*256 + co)*32 + (c&31)
//   wqkbn: (t, tap, o, c) -> (((t*3+tap)*8 + (c>>5))*16 + o)*32 + (c&31)
//   qb/kb frag-major: f = b*128 + (n>>5); addr = f*512 + (n&31 + 32*(o>>3))*8 + (o&7)
//   vb frag-major:    f = (b*8 + (c>>5))*256 + (n>>4); addr = f*512 + (c&31 + 32*((n>>3)&1))*8 + (n&7)
// nu2 slot layout: [0..127] f32 ssq/ssk sums; ints at byte offset 1024: cnt[4] per-b tickets.

// ================= phase bodies ==========

__device__ __forceinline__ void prep_tile_body(
        int vb, const float* __restrict__ x, unsigned short* __restrict__ xT,
        float (*tile_t)[65], int tid) {
    int nt = vb & 63, ct = (vb >> 6) & 3, b = vb >> 8;
    int n0 = nt * 64, c0 = ct * 64;
    int rg = tid >> 4, f = tid & 15;
    const float* xb = x + ((size_t)b * CC + c0) * NN + n0;
#pragma unroll
    for (int p = 0; p < 4; ++p) {
        int c = p * 16 + rg;
        float4 v = *(const float4*)(xb + (size_t)c * NN + f * 4);
        tile_t[f * 4 + 0][c] = v.x;
        tile_t[f * 4 + 1][c] = v.y;
        tile_t[f * 4 + 2][c] = v.z;
        tile_t[f * 4 + 3][c] = v.w;
    }
    __syncthreads();
    // K-chunked store: c = c0 + f*4 + j -> kq = ct*2 + (f>>3), cc = (f&7)*4 + j
    unsigned short* xtb = xT + (((size_t)b * 8 + ct * 2 + (f >> 3)) * NN + n0) * 32 + (f & 7) * 4;
#pragma unroll
    for (int p = 0; p < 4; ++p) {
        int n = p * 16 + rg;
        ushort4 st;
        st.x = f2bf(tile_t[n][f * 4 + 0]);
        st.y = f2bf(tile_t[n][f * 4 + 1]);
        st.z = f2bf(tile_t[n][f * 4 + 2]);
        st.w = f2bf(tile_t[n][f * 4 + 3]);
        *(ushort4*)(xtb + (size_t)n * 32) = st;
    }
}

__device__ __forceinline__ void prep_wt_body(
        int vb, const float* __restrict__ wv, const float* __restrict__ wq,
        const float* __restrict__ wk, unsigned short* __restrict__ wvb,
        unsigned short* __restrict__ wqkb, float* __restrict__ nu2, int tid) {
    int idx = (vb - 1024) * 256 + tid;
    if (vb == 1024) {
        if (tid < 128) nu2[tid] = 0.f;
        else if (tid < 132) ((int*)((char*)nu2 + 1024))[tid - 128] = 0;   // per-b tickets
    }
    if (idx < 16384) {
        float4 v = *(const float4*)(wv + idx * 4);
        ushort4 o;
        o.x = f2bf(v.x); o.y = f2bf(v.y); o.z = f2bf(v.z); o.w = f2bf(v.w);
        int e0 = idx * 4;
        int co = e0 >> 8, c = e0 & 255;
        *(ushort4*)(wvb + ((size_t)(c >> 5) * 256 + co) * 32 + (c & 31)) = o;
    } else if (idx < 16384 + 6144) {
        int base = (idx - 16384) * 4;
#pragma unroll
        for (int u = 0; u < 4; ++u) {
            int e = base + u;
            int t = e / 12288;
            int i = e - t * 12288;
            int tap = i >> 12, o = (i >> 8) & 15, c = i & 255;
            const float* src = t ? wk : wq;
            wqkb[(((size_t)(t * 3 + tap) * 8 + (c >> 5)) * 16 + o) * 32 + (c & 31)]
                = f2bf(src[o * 768 + c * 3 + tap]);
        }
    }
}

__device__ __forceinline__ void conv_v_body(
        int vb, const unsigned short* __restrict__ xT, const unsigned short* __restrict__ wvb,
        const float* __restrict__ bv, unsigned short* __restrict__ vbuf, int tid) {
    int wv_ = tid >> 6, lane = tid & 63;
    int q16 = lane >> 4, c16 = lane & 15;
    int ntile = vb & 63, b = (vb >> 6) & 3, ch = vb >> 8;
    int n0 = ntile * 64;
    int cb = ch * 128 + wv_ * 32;
    floatx4 fzero = {0.f, 0.f, 0.f, 0.f};
    floatx4 acc[2][4];
    for (int ct = 0; ct < 2; ++ct)
        for (int nt = 0; nt < 4; ++nt) acc[ct][nt] = fzero;
    int lo8 = q16 * 8;
    for (int kc = 0; kc < 8; ++kc) {
        const unsigned short* xk = xT + (((size_t)b * 8 + kc) * NN + n0) * 32;
        const unsigned short* wk_ = wvb + ((size_t)kc * 256 + cb) * 32;
        short8 a0 = *(const short8*)(wk_ + c16 * 32 + lo8);
        short8 a1 = *(const short8*)(wk_ + (16 + c16) * 32 + lo8);
        short8 bf[4];
#pragma unroll
        for (int nt = 0; nt < 4; ++nt)
            bf[nt] = *(const short8*)(xk + (nt * 16 + c16) * 32 + lo8);
#pragma unroll
        for (int nt = 0; nt < 4; ++nt) {
            acc[0][nt] = __builtin_amdgcn_mfma_f32_16x16x32_bf16(bf[nt], a0, acc[0][nt], 0, 0, 0);
            acc[1][nt] = __builtin_amdgcn_mfma_f32_16x16x32_bf16(bf[nt], a1, acc[1][nt], 0, 0, 0);
        }
    }
    float bv0 = bv[cb + c16], bv1 = bv[cb + 16 + c16];
    int off = 32 * 8 * (q16 >> 1) + (q16 & 1) * 4 + c16 * 8;
#pragma unroll
    for (int ct = 0; ct < 2; ++ct) {
        float bvv = ct ? bv1 : bv0;
#pragma unroll
        for (int nt = 0; nt < 4; ++nt) {
            size_t fb = (((size_t)b * 8 + ch * 4 + wv_) * 256 + (n0 >> 4) + nt) * 512;
            ushort4 st;
            st.x = f2bf(acc[ct][nt][0] + bvv);
            st.y = f2bf(acc[ct][nt][1] + bvv);
            st.z = f2bf(acc[ct][nt][2] + bvv);
            st.w = f2bf(acc[ct][nt][3] + bvv);
            *(ushort4*)(vbuf + fb + off + ct * 16 * 8) = st;
        }
    }
}

// FRN + Mish (unchanged math). blk = tensor*256 + b*64 + nch.
__device__ __forceinline__ void frn_body(
        int blk, const unsigned short* __restrict__ qrawh, const unsigned short* __restrict__ krawh,
        const float* __restrict__ nu2, const float* __restrict__ eps_q,
        const float* __restrict__ eps_k, unsigned short* __restrict__ qb,
        unsigned short* __restrict__ kb, int tid) {
    int tensor = blk >> 8;
    int b = (blk >> 6) & 3;
    int nch = blk & 63;
    const unsigned short* raw = tensor ? krawh : qrawh;
    const float* eps = tensor ? eps_k : eps_q;
    unsigned short* outp = tensor ? kb : qb;
    const float* nu = nu2 + tensor * 64 + b * C16;
    float scale = tensor ? 1.0f : 1.44269504f;
    int n = nch * 64 + (tid & 63);
    int oq = tid >> 6;
    ushort4 pk4;
#pragma unroll
    for (int i = 0; i < 4; ++i) {
        int o = oq * 4 + i;
        float r = bf2f(raw[(size_t)(b * C16 + o) * NN + n]);
        float v = r * rsqrtf(nu[o] * (1.f / (float)NN) + fabsf(eps[o]));
        float t = EXP2(v * 1.44269504f);
        float num = t * t + 2.0f * t;
        float m = (v * num) * __builtin_amdgcn_rcpf(num + 2.0f);
        if (v > 30.f) m = v;
        m *= scale;
        ((unsigned short*)&pk4)[i] = f2bf(m);
    }
    size_t base = ((size_t)b * 128 + (n >> 5)) * 512 + (size_t)(n & 31) * 8
                + (size_t)(oq >> 1) * 256 + (oq & 1) * 4;
    *(ushort4*)(outp + base) = pk4;
}

// frn for one whole b (2 tensors x 64 n-chunks), run by the LAST conv_qk block of b.
__device__ __forceinline__ void frn_for_b(
        int b, const unsigned short* __restrict__ qrawh, const unsigned short* __restrict__ krawh,
        const float* __restrict__ nu2, const float* __restrict__ eps_q,
        const float* __restrict__ eps_k, unsigned short* __restrict__ qb,
        unsigned short* __restrict__ kb, int tid) {
#pragma unroll 4
    for (int seg = 0; seg < 128; ++seg) {
        int tensor = seg >> 6;
        int nch = seg & 63;
        frn_body((tensor << 8) | (b << 6) | nch, qrawh, krawh, nu2, eps_q, eps_k,
                 qb, kb, tid);
    }
}

// conv_qk: 1 MFMA unit/block, K split across 4 waves, LDS reduce, K-chunked loads.
// Epilogue: device-scope ticket; last block of b runs frn_for_b inline.
__device__ __forceinline__ void conv_qk_body_v2(
        int u, const unsigned short* __restrict__ xT, const unsigned short* __restrict__ wqkb,
        const float* __restrict__ bq, const float* __restrict__ bk,
        unsigned short* __restrict__ qrawh, unsigned short* __restrict__ krawh,
        float* __restrict__ nu2, const float* __restrict__ eps_q,
        const float* __restrict__ eps_k, unsigned short* __restrict__ qb,
        unsigned short* __restrict__ kb, int tid,
        float4 (*redq)[64], float4 (*redk)[64], int* lastflag) {
    int w = tid >> 6, lane = tid & 63;
    int q16 = lane >> 4, c16 = lane & 15;
    int b = u >> 8, unit = u & 255;
    int n0 = unit * 16;
    int nl = n0 + c16;
    int hh = nl >> 6, ww = nl & 63;
    bool vm1 = (ww != 0), vp1 = (ww != 63);
    bool vm64 = (hh != 0), vp64 = (hh != 63);
    short8 zero8 = {0, 0, 0, 0, 0, 0, 0, 0};
    floatx4 accq = {0.f, 0.f, 0.f, 0.f}, acck = {0.f, 0.f, 0.f, 0.f};
    int lo8 = q16 * 8;
#pragma unroll
    for (int kk = 0; kk < 2; ++kk) {
        int kc = w * 2 + kk;
        const unsigned short* xk = xT + (((size_t)b * 8 + kc) * NN) * 32;
        short8 b0 = *(const short8*)(xk + (size_t)nl * 32 + lo8);
        short8 bm1 = vm1 ? *(const short8*)(xk + (size_t)(nl - 1) * 32 + lo8) : zero8;
        short8 bp1 = vp1 ? *(const short8*)(xk + (size_t)(nl + 1) * 32 + lo8) : zero8;
        short8 bm64 = vm64 ? *(const short8*)(xk + (size_t)(nl - 64) * 32 + lo8) : zero8;
        short8 bp64 = vp64 ? *(const short8*)(xk + (size_t)(nl + 64) * 32 + lo8) : zero8;
        int wbase = kc * 512 + c16 * 32 + lo8;
        short8 aq0 = *(const short8*)(wqkb + 0 * 4096 + wbase);
        short8 aq1 = *(const short8*)(wqkb + 1 * 4096 + wbase);
        short8 aq2 = *(const short8*)(wqkb + 2 * 4096 + wbase);
        short8 ak0 = *(const short8*)(wqkb + 12288 + 0 * 4096 + wbase);
        short8 ak1 = *(const short8*)(wqkb + 12288 + 1 * 4096 + wbase);
        short8 ak2 = *(const short8*)(wqkb + 12288 + 2 * 4096 + wbase);
        accq = __builtin_amdgcn_mfma_f32_16x16x32_bf16(bm1, aq0, accq, 0, 0, 0);
        accq = __builtin_amdgcn_mfma_f32_16x16x32_bf16(b0, aq1, accq, 0, 0, 0);
        accq = __builtin_amdgcn_mfma_f32_16x16x32_bf16(bp1, aq2, accq, 0, 0, 0);
        acck = __builtin_amdgcn_mfma_f32_16x16x32_bf16(bm64, ak0, acck, 0, 0, 0);
        acck = __builtin_amdgcn_mfma_f32_16x16x32_bf16(b0, ak1, acck, 0, 0, 0);
        acck = __builtin_amdgcn_mfma_f32_16x16x32_bf16(bp64, ak2, acck, 0, 0, 0);
    }
    float4 pq, pk;
    pq.x = accq[0]; pq.y = accq[1]; pq.z = accq[2]; pq.w = accq[3];
    pk.x = acck[0]; pk.y = acck[1]; pk.z = acck[2]; pk.w = acck[3];
    redq[w][lane] = pq;
    redk[w][lane] = pk;
    __syncthreads();
    if (w == 0) {
        float4 a0 = redq[0][lane], a1 = redq[1][lane], a2 = redq[2][lane], a3 = redq[3][lane];
        float s0 = ((a0.x + a1.x) + a2.x) + a3.x;
        float s1 = ((a0.y + a1.y) + a2.y) + a3.y;
        float s2 = ((a0.z + a1.z) + a2.z) + a3.z;
        float s3 = ((a0.w + a1.w) + a2.w) + a3.w;
        float bqv = bq[c16];
        float vq0 = s0 + bqv, vq1 = s1 + bqv, vq2 = s2 + bqv, vq3 = s3 + bqv;
        ushort4 sq4;
        sq4.x = f2bf(vq0); sq4.y = f2bf(vq1); sq4.z = f2bf(vq2); sq4.w = f2bf(vq3);
        *(ushort4*)(qrawh + (size_t)(b * C16 + c16) * NN + n0 + q16 * 4) = sq4;
        float ssq = vq0 * vq0 + vq1 * vq1 + vq2 * vq2 + vq3 * vq3;
        ssq += __shfl_xor(ssq, 16, 64);
        ssq += __shfl_xor(ssq, 32, 64);
        if (lane < 16) atomicAdd(nu2 + b * C16 + lane, ssq);
    } else if (w == 1) {
        float4 a0 = redk[0][lane], a1 = redk[1][lane], a2 = redk[2][lane], a3 = redk[3][lane];
        float s0 = ((a0.x + a1.x) + a2.x) + a3.x;
        float s1 = ((a0.y + a1.y) + a2.y) + a3.y;
        float s2 = ((a0.z + a1.z) + a2.z) + a3.z;
        float s3 = ((a0.w + a1.w) + a2.w) + a3.w;
        float bkv = bk[c16];
        float vk0 = s0 + bkv, vk1 = s1 + bkv, vk2 = s2 + bkv, vk3 = s3 + bkv;
        ushort4 sk4;
        sk4.x = f2bf(vk0); sk4.y = f2bf(vk1); sk4.z = f2bf(vk2); sk4.w = f2bf(vk3);
        *(ushort4*)(krawh + (size_t)(b * C16 + c16) * NN + n0 + q16 * 4) = sk4;
        float ssk = vk0 * vk0 + vk1 * vk1 + vk2 * vk2 + vk3 * vk3;
        ssk += __shfl_xor(ssk, 16, 64);
        ssk += __shfl_xor(ssk, 32, 64);
        if (lane < 16) atomicAdd(nu2 + 64 + b * C16 + lane, ssk);
    }
    // ----- ticket: last block of this b runs frn for the whole b -----
    int* cnt = (int*)((char*)nu2 + 1024);
    __threadfence();                 // release: q/k raw stores visible device-wide
    __syncthreads();
    if (tid == 0) {
        int old = atomicAdd(cnt + b, 1);
        *lastflag = (old == 255);    // 256 qk units per b
    }
    __syncthreads();
    if (*lastflag) {
        __threadfence();             // acquire: see all other blocks' stores
        frn_for_b(b, qrawh, krawh, nu2, eps_q, eps_k, qb, kb, tid);
    }
}

// exp2 half-pack: 8 score elems -> one bf16 A-frag word via v_permlane32_swap_b32.
__device__ __forceinline__ void pack_half(
        const floatx16& sc, int h, short8* A, float* lsum) {
    unsigned pk[4];
    float ls = 0.f;
#pragma unroll
    for (int p = 0; p < 4; ++p) {
        float e0 = EXP2(sc[8 * h + 2 * p]);
        float e1 = EXP2(sc[8 * h + 2 * p + 1]);
        ls += e0 + e1;
        pk[p] = __builtin_amdgcn_perm(__float_as_uint(e1), __float_as_uint(e0), 0x07060302u);
    }
    *lsum += ls;
    asm("v_permlane32_swap_b32 %0, %1" : "+v"(pk[0]), "+v"(pk[2]));
    asm("v_permlane32_swap_b32 %0, %1" : "+v"(pk[1]), "+v"(pk[3]));
    union { unsigned u[4]; short8 s; } a;
    a.u[0] = pk[0]; a.u[1] = pk[1]; a.u[2] = pk[2]; a.u[3] = pk[3];
    *A = a.s;
}

// attention body: j=64 c=128 per block, split-pack interleaved (r3 structure)
__device__ __forceinline__ void attn_body(
        int id, const unsigned short* __restrict__ qb, const unsigned short* __restrict__ kb,
        const unsigned short* __restrict__ vbuf, const float* __restrict__ x,
        const float* __restrict__ gamma_p, float* __restrict__ out,
        float (*lpart)[2][32], float (*obuf)[32][33], int tid) {
    int wv_ = __builtin_amdgcn_readfirstlane(tid >> 6);
    int lane = tid & 63;
    int l31 = lane & 31, lh = lane >> 5;
    int cs = id & 1, b = (id >> 1) & 3, jt = id >> 3;
    int jbase = jt * 64, cb = cs * 128;
    int lane8 = lane * 8;

    const unsigned short* qfb = qb + ((size_t)b * 128 + (jbase >> 5)) * 512 + lane8;
    const unsigned short* kfb = kb + ((size_t)b * 128 + (wv_ * 32)) * 512 + lane8;

    short8 qf0 = *(const short8*)qfb;
    short8 qf1 = *(const short8*)(qfb + 512);

    floatx16 z16 = {0,0,0,0,0,0,0,0,0,0,0,0,0,0,0,0};
    floatx16 acc0[4], acc1[4];
#pragma unroll
    for (int cg = 0; cg < 4; ++cg) { acc0[cg] = z16; acc1[cg] = z16; }
    float lsum0 = 0.f, lsum1 = 0.f;

    const unsigned short* vp0 = vbuf + (((size_t)b * 8 + cs * 4 + 0) * 256 + wv_ * 64) * 512 + lane8;
    const unsigned short* vp1 = vbuf + (((size_t)b * 8 + cs * 4 + 1) * 256 + wv_ * 64) * 512 + lane8;
    const unsigned short* vp2 = vbuf + (((size_t)b * 8 + cs * 4 + 2) * 256 + wv_ * 64) * 512 + lane8;
    const unsigned short* vp3 = vbuf + (((size_t)b * 8 + cs * 4 + 3) * 256 + wv_ * 64) * 512 + lane8;

    short8 ak = *(const short8*)kfb;
#pragma unroll 1
    for (int step = 0; step < 32; ++step) {
        short8 vf0a = *(const short8*)vp0;
        short8 vf1a = *(const short8*)vp1;
        short8 vf2a = *(const short8*)vp2;
        short8 vf3a = *(const short8*)vp3;
        short8 vf0b = *(const short8*)(vp0 + 512);
        short8 vf1b = *(const short8*)(vp1 + 512);
        short8 vf2b = *(const short8*)(vp2 + 512);
        short8 vf3b = *(const short8*)(vp3 + 512);
        floatx16 sc0 = __builtin_amdgcn_mfma_f32_32x32x16_bf16(ak, qf0, z16, 0, 0, 0);
        floatx16 sc1 = __builtin_amdgcn_mfma_f32_32x32x16_bf16(ak, qf1, z16, 0, 0, 0);
        ak = *(const short8*)(kfb + (size_t)((step + 1) & 31) * 512);
        short8 A;
        pack_half(sc0, 0, &A, &lsum0);                 // A00
        __builtin_amdgcn_s_setprio(1);
        acc0[0] = __builtin_amdgcn_mfma_f32_32x32x16_bf16(A, vf0a, acc0[0], 0, 0, 0);
        acc0[1] = __builtin_amdgcn_mfma_f32_32x32x16_bf16(A, vf1a, acc0[1], 0, 0, 0);
        acc0[2] = __builtin_amdgcn_mfma_f32_32x32x16_bf16(A, vf2a, acc0[2], 0, 0, 0);
        acc0[3] = __builtin_amdgcn_mfma_f32_32x32x16_bf16(A, vf3a, acc0[3], 0, 0, 0);
        __builtin_amdgcn_s_setprio(0);
        __builtin_amdgcn_sched_barrier(0);
        pack_half(sc0, 1, &A, &lsum0);                 // A01
        __builtin_amdgcn_s_setprio(1);
        acc0[0] = __builtin_amdgcn_mfma_f32_32x32x16_bf16(A, vf0b, acc0[0], 0, 0, 0);
        acc0[1] = __builtin_amdgcn_mfma_f32_32x32x16_bf16(A, vf1b, acc0[1], 0, 0, 0);
        acc0[2] = __builtin_amdgcn_mfma_f32_32x32x16_bf16(A, vf2b, acc0[2], 0, 0, 0);
        acc0[3] = __builtin_amdgcn_mfma_f32_32x32x16_bf16(A, vf3b, acc0[3], 0, 0, 0);
        __builtin_amdgcn_s_setprio(0);
        __builtin_amdgcn_sched_barrier(0);
        pack_half(sc1, 0, &A, &lsum1);                 // A10
        __builtin_amdgcn_s_setprio(1);
        acc1[0] = __builtin_amdgcn_mfma_f32_32x32x16_bf16(A, vf0a, acc1[0], 0, 0, 0);
        acc1[1] = __builtin_amdgcn_mfma_f32_32x32x16_bf16(A, vf1a, acc1[1], 0, 0, 0);
        acc1[2] = __builtin_amdgcn_mfma_f32_32x32x16_bf16(A, vf2a, acc1[2], 0, 0, 0);
        acc1[3] = __builtin_amdgcn_mfma_f32_32x32x16_bf16(A, vf3a, acc1[3], 0, 0, 0);
        __builtin_amdgcn_s_setprio(0);
        __builtin_amdgcn_sched_barrier(0);
        pack_half(sc1, 1, &A, &lsum1);                 // A11
        __builtin_amdgcn_s_setprio(1);
        acc1[0] = __builtin_amdgcn_mfma_f32_32x32x16_bf16(A, vf0b, acc1[0], 0, 0, 0);
        acc1[1] = __builtin_amdgcn_mfma_f32_32x32x16_bf16(A, vf1b, acc1[1], 0, 0, 0);
        acc1[2] = __builtin_amdgcn_mfma_f32_32x32x16_bf16(A, vf2b, acc1[2], 0, 0, 0);
        acc1[3] = __builtin_amdgcn_mfma_f32_32x32x16_bf16(A, vf3b, acc1[3], 0, 0, 0);
        __builtin_amdgcn_s_setprio(0);
        vp0 += 1024; vp1 += 1024; vp2 += 1024; vp3 += 1024;
    }

    lsum0 += __shfl_xor(lsum0, 32, 64);
    lsum1 += __shfl_xor(lsum1, 32, 64);
    if (lh == 0) { lpart[wv_][0][l31] = lsum0; lpart[wv_][1][l31] = lsum1; }
    __syncthreads();

    int j31 = tid & 31;
    float gamma = gamma_p[0];
    float gl0 = gamma / (lpart[0][0][j31] + lpart[1][0][j31] + lpart[2][0][j31] + lpart[3][0][j31]);
    float gl1 = gamma / (lpart[0][1][j31] + lpart[1][1][j31] + lpart[2][1][j31] + lpart[3][1][j31]);
    const float* xbb = x + (size_t)b * CC * NN;
    float* obb = out + (size_t)b * CC * NN;
    int hofs = lh * 4;
    int cgrp = tid >> 5;
#pragma unroll
    for (int jg = 0; jg < 2; ++jg) {
        float gl = jg ? gl1 : gl0;
#pragma unroll
        for (int cg = 0; cg < 4; ++cg) {
            __syncthreads();
            const floatx16& a = jg ? acc1[cg] : acc0[cg];
#pragma unroll
            for (int r = 0; r < 16; ++r) {
                int row = (r & 3) + 8 * (r >> 2) + hofs;
                obuf[wv_][row][l31] = a[r];
            }
            __syncthreads();
#pragma unroll
            for (int i = 0; i < 4; ++i) {
                int c = cgrp * 4 + i;
                float val = obuf[0][j31][c] + obuf[1][j31][c] + obuf[2][j31][c] + obuf[3][j31][c];
                size_t oidx = (size_t)(cb + cg * 32 + c) * NN + jbase + jg * 32 + j31;
                obb[oidx] = fmaf(gl, val, xbb[oidx]);
            }
        }
    }
}

// ================= kernels ==========
__global__ __launch_bounds__(256) void prep_kernel(
        const float* __restrict__ x, const float* __restrict__ wv,
        const float* __restrict__ wq, const float* __restrict__ wk,
        unsigned short* __restrict__ xT, unsigned short* __restrict__ wvb,
        unsigned short* __restrict__ wqkb, float* __restrict__ nu2) {
    __shared__ float tile_t[64][65];
    int bid = blockIdx.x;
    if (bid < 1024) prep_tile_body(bid, x, xT, tile_t, threadIdx.x);
    else prep_wt_body(bid, wv, wq, wk, wvb, wqkb, nu2, threadIdx.x);
}

// grid 1536: blocks 0..511 conv_v, 512..1535 conv_qk (1024 units) + frn epilogue.
__global__ __launch_bounds__(256) void conv_kernel(
        const unsigned short* __restrict__ xT, const unsigned short* __restrict__ wvb,
        const unsigned short* __restrict__ wqkb, const float* __restrict__ bv,
        const float* __restrict__ bq, const float* __restrict__ bk,
        unsigned short* __restrict__ vbuf, unsigned short* __restrict__ qrawh,
        unsigned short* __restrict__ krawh, float* __restrict__ nu2,
        const float* __restrict__ eps_q, const float* __restrict__ eps_k,
        unsigned short* __restrict__ qb, unsigned short* __restrict__ kb) {
    __shared__ float4 redq[4][64];
    __shared__ float4 redk[4][64];
    __shared__ int lastflag;
    int bid = blockIdx.x;
    if (bid < 512) conv_v_body(bid, xT, wvb, bv, vbuf, threadIdx.x);
    else conv_qk_body_v2(bid - 512, xT, wqkb, bq, bk, qrawh, krawh, nu2,
                         eps_q, eps_k, qb, kb, threadIdx.x, redq, redk, &lastflag);
}

__global__ __launch_bounds__(256, 2) void attn_kernel(
        const unsigned short* __restrict__ qb, const unsigned short* __restrict__ kb,
        const unsigned short* __restrict__ vbuf, const float* __restrict__ x,
        const float* __restrict__ gamma_p, float* __restrict__ out) {
    __shared__ float lpart[4][2][32];
    __shared__ float obuf[4][32][33];
    attn_body(blockIdx.x, qb, kb, vbuf, x, gamma_p, out, lpart, obuf, threadIdx.x);
}

extern "C" void kernel_launch(void* const* d_in, const int* in_sizes, int n_in,
                              void* d_out, int out_size, void* d_ws, size_t ws_size,
                              hipStream_t stream) {
    const float* x     = (const float*)d_in[0];
    const float* wq    = (const float*)d_in[1];
    const float* bq    = (const float*)d_in[2];
    const float* wk    = (const float*)d_in[3];
    const float* bk    = (const float*)d_in[4];
    const float* wv    = (const float*)d_in[5];
    const float* bv    = (const float*)d_in[6];
    const float* gamma = (const float*)d_in[7];
    const float* eps_q = (const float*)d_in[8];
    const float* eps_k = (const float*)d_in[9];
    float* out = (float*)d_out;
    char* ws = (char*)d_ws;

    unsigned short* qrawh = (unsigned short*)ws;
    unsigned short* krawh = (unsigned short*)(ws + (1u << 20));
    float* nu2  = (float*)(ws + (2u << 20));
    unsigned short* qb = (unsigned short*)(ws + (2u << 20) + 4096);
    unsigned short* kb = qb + (size_t)NB * NN * C16;
    unsigned short* vbuf = kb + (size_t)NB * NN * C16;
    unsigned short* xT = vbuf + (size_t)NB * CC * NN;
    unsigned short* wvb = xT + (size_t)NB * NN * CC;
    unsigned short* wqkb = wvb + (size_t)CC * CC;

    prep_kernel<<<dim3(1112), dim3(256), 0, stream>>>(x, wv, wq, wk, xT, wvb, wqkb, nu2);
    conv_kernel<<<dim3(1536), dim3(256), 0, stream>>>(xT, wvb, wqkb, bv, bq, bk, vbuf,
                                                      qrawh, krawh, nu2, eps_q, eps_k, qb, kb);
    attn_kernel<<<dim3(512), dim3(256), 0, stream>>>(qb, kb, vbuf, x, gamma, out);
}

// Round 13
// 151.417 us; speedup vs baseline: 1.8593x; 1.8593x over previous
//
#include <hip/hip_runtime.h>
#include <stdint.h>

#define NB 4
#define CC 256
#define C16 16
#define HH 64
#define WW 64
#define NN 4096

typedef __attribute__((ext_vector_type(8))) short short8;
typedef __attribute__((ext_vector_type(4))) float floatx4;
typedef __attribute__((ext_vector_type(16))) float floatx16;

#if __has_builtin(__builtin_amdgcn_exp2f)
#define EXP2(x) __builtin_amdgcn_exp2f(x)
#else
#define EXP2(x) exp2f(x)
#endif

__device__ __forceinline__ unsigned short f2bf(float f) {
    union { float f; unsigned u; } v; v.f = f;
    unsigned r = v.u + 0x7fffu + ((v.u >> 16) & 1u);
    return (unsigned short)(r >> 16);
}
__device__ __forceinline__ float bf2f(unsigned short h) {
    union { unsigned u; float f; } v; v.u = (unsigned)h << 16;
    return v.f;
}

// Layouts:
//   xTn (K-chunked): elem (b, n, c), kq=c>>5, cc=c&31 -> ((b*8+kq)*4096 + n)*32 + cc
//     -> a wave's 16-row x 16B load is 1KB CONTIGUOUS (1 transaction vs 16).
//   wvbn: (co, c) -> ((c>>5)*256 + co)*32 + (c&31)
//   wqkbn: (t, tap, o, c) -> (((t*3+tap)*8 + (c>>5))*16 + o)*32 + (c&31)
//   qb/kb frag-major: f = b*128 + (n>>5); addr = f*512 + (n&31 + 32*(o>>3))*8 + (o&7)
//   vb frag-major:    f = (b*8 + (c>>5))*256 + (n>>4); addr = f*512 + (c&31 + 32*((n>>3)&1))*8 + (n&7)

// ================= phase bodies ==========

__device__ __forceinline__ void prep_tile_body(
        int vb, const float* __restrict__ x, unsigned short* __restrict__ xT,
        float (*tile_t)[65], int tid) {
    int nt = vb & 63, ct = (vb >> 6) & 3, b = vb >> 8;
    int n0 = nt * 64, c0 = ct * 64;
    int rg = tid >> 4, f = tid & 15;
    const float* xb = x + ((size_t)b * CC + c0) * NN + n0;
#pragma unroll
    for (int p = 0; p < 4; ++p) {
        int c = p * 16 + rg;
        float4 v = *(const float4*)(xb + (size_t)c * NN + f * 4);
        tile_t[f * 4 + 0][c] = v.x;
        tile_t[f * 4 + 1][c] = v.y;
        tile_t[f * 4 + 2][c] = v.z;
        tile_t[f * 4 + 3][c] = v.w;
    }
    __syncthreads();
    // K-chunked store: c = c0 + f*4 + j -> kq = ct*2 + (f>>3), cc = (f&7)*4 + j
    unsigned short* xtb = xT + (((size_t)b * 8 + ct * 2 + (f >> 3)) * NN + n0) * 32 + (f & 7) * 4;
#pragma unroll
    for (int p = 0; p < 4; ++p) {
        int n = p * 16 + rg;
        ushort4 st;
        st.x = f2bf(tile_t[n][f * 4 + 0]);
        st.y = f2bf(tile_t[n][f * 4 + 1]);
        st.z = f2bf(tile_t[n][f * 4 + 2]);
        st.w = f2bf(tile_t[n][f * 4 + 3]);
        *(ushort4*)(xtb + (size_t)n * 32) = st;
    }
}

__device__ __forceinline__ void prep_wt_body(
        int vb, const float* __restrict__ wv, const float* __restrict__ wq,
        const float* __restrict__ wk, unsigned short* __restrict__ wvb,
        unsigned short* __restrict__ wqkb, float* __restrict__ nu2, int tid) {
    int idx = (vb - 1024) * 256 + tid;
    if (vb == 1024 && tid < 128) nu2[tid] = 0.f;
    if (idx < 16384) {
        float4 v = *(const float4*)(wv + idx * 4);
        ushort4 o;
        o.x = f2bf(v.x); o.y = f2bf(v.y); o.z = f2bf(v.z); o.w = f2bf(v.w);
        int e0 = idx * 4;
        int co = e0 >> 8, c = e0 & 255;   // 4 consecutive c, same 32-chunk, same co
        *(ushort4*)(wvb + ((size_t)(c >> 5) * 256 + co) * 32 + (c & 31)) = o;
    } else if (idx < 16384 + 6144) {
        int base = (idx - 16384) * 4;
#pragma unroll
        for (int u = 0; u < 4; ++u) {
            int e = base + u;
            int t = e / 12288;
            int i = e - t * 12288;
            int tap = i >> 12, o = (i >> 8) & 15, c = i & 255;
            const float* src = t ? wk : wq;
            wqkb[(((size_t)(t * 3 + tap) * 8 + (c >> 5)) * 16 + o) * 32 + (c & 31)]
                = f2bf(src[o * 768 + c * 3 + tap]);
        }
    }
}

__device__ __forceinline__ void conv_v_body(
        int vb, const unsigned short* __restrict__ xT, const unsigned short* __restrict__ wvb,
        const float* __restrict__ bv, unsigned short* __restrict__ vbuf, int tid) {
    int wv_ = tid >> 6, lane = tid & 63;
    int q16 = lane >> 4, c16 = lane & 15;
    int ntile = vb & 63, b = (vb >> 6) & 3, ch = vb >> 8;
    int n0 = ntile * 64;
    int cb = ch * 128 + wv_ * 32;
    floatx4 fzero = {0.f, 0.f, 0.f, 0.f};
    floatx4 acc[2][4];
    for (int ct = 0; ct < 2; ++ct)
        for (int nt = 0; nt < 4; ++nt) acc[ct][nt] = fzero;
    int lo8 = q16 * 8;
    for (int kc = 0; kc < 8; ++kc) {
        const unsigned short* xk = xT + (((size_t)b * 8 + kc) * NN + n0) * 32;
        const unsigned short* wk_ = wvb + ((size_t)kc * 256 + cb) * 32;
        short8 a0 = *(const short8*)(wk_ + c16 * 32 + lo8);
        short8 a1 = *(const short8*)(wk_ + (16 + c16) * 32 + lo8);
        short8 bf[4];
#pragma unroll
        for (int nt = 0; nt < 4; ++nt)
            bf[nt] = *(const short8*)(xk + (nt * 16 + c16) * 32 + lo8);
#pragma unroll
        for (int nt = 0; nt < 4; ++nt) {
            acc[0][nt] = __builtin_amdgcn_mfma_f32_16x16x32_bf16(bf[nt], a0, acc[0][nt], 0, 0, 0);
            acc[1][nt] = __builtin_amdgcn_mfma_f32_16x16x32_bf16(bf[nt], a1, acc[1][nt], 0, 0, 0);
        }
    }
    float bv0 = bv[cb + c16], bv1 = bv[cb + 16 + c16];
    int off = 32 * 8 * (q16 >> 1) + (q16 & 1) * 4 + c16 * 8;
#pragma unroll
    for (int ct = 0; ct < 2; ++ct) {
        float bvv = ct ? bv1 : bv0;
#pragma unroll
        for (int nt = 0; nt < 4; ++nt) {
            size_t fb = (((size_t)b * 8 + ch * 4 + wv_) * 256 + (n0 >> 4) + nt) * 512;
            ushort4 st;
            st.x = f2bf(acc[ct][nt][0] + bvv);
            st.y = f2bf(acc[ct][nt][1] + bvv);
            st.z = f2bf(acc[ct][nt][2] + bvv);
            st.w = f2bf(acc[ct][nt][3] + bvv);
            *(ushort4*)(vbuf + fb + off + ct * 16 * 8) = st;
        }
    }
}

// conv_qk: 1 MFMA unit/block (1024 blocks), K split across the 4 waves
// (wave w: kc in {2w, 2w+1}), partials reduced via LDS; K-chunked loads are
// wave-contiguous. Wave 0 finishes q, wave 1 finishes k.
__device__ __forceinline__ void conv_qk_body_v2(
        int u, const unsigned short* __restrict__ xT, const unsigned short* __restrict__ wqkb,
        const float* __restrict__ bq, const float* __restrict__ bk,
        unsigned short* __restrict__ qrawh, unsigned short* __restrict__ krawh,
        float* __restrict__ nu2, int tid,
        float4 (*redq)[64], float4 (*redk)[64]) {
    int w = tid >> 6, lane = tid & 63;
    int q16 = lane >> 4, c16 = lane & 15;
    int b = u >> 8, unit = u & 255;
    int n0 = unit * 16;
    int nl = n0 + c16;                     // A-frag m row (global n)
    int hh = nl >> 6, ww = nl & 63;
    bool vm1 = (ww != 0), vp1 = (ww != 63);
    bool vm64 = (hh != 0), vp64 = (hh != 63);
    short8 zero8 = {0, 0, 0, 0, 0, 0, 0, 0};
    floatx4 accq = {0.f, 0.f, 0.f, 0.f}, acck = {0.f, 0.f, 0.f, 0.f};
    int lo8 = q16 * 8;
#pragma unroll
    for (int kk = 0; kk < 2; ++kk) {
        int kc = w * 2 + kk;
        const unsigned short* xk = xT + (((size_t)b * 8 + kc) * NN) * 32;
        short8 b0 = *(const short8*)(xk + (size_t)nl * 32 + lo8);
        short8 bm1 = vm1 ? *(const short8*)(xk + (size_t)(nl - 1) * 32 + lo8) : zero8;
        short8 bp1 = vp1 ? *(const short8*)(xk + (size_t)(nl + 1) * 32 + lo8) : zero8;
        short8 bm64 = vm64 ? *(const short8*)(xk + (size_t)(nl - 64) * 32 + lo8) : zero8;
        short8 bp64 = vp64 ? *(const short8*)(xk + (size_t)(nl + 64) * 32 + lo8) : zero8;
        int wbase = kc * 512 + c16 * 32 + lo8;
        short8 aq0 = *(const short8*)(wqkb + 0 * 4096 + wbase);
        short8 aq1 = *(const short8*)(wqkb + 1 * 4096 + wbase);
        short8 aq2 = *(const short8*)(wqkb + 2 * 4096 + wbase);
        short8 ak0 = *(const short8*)(wqkb + 12288 + 0 * 4096 + wbase);
        short8 ak1 = *(const short8*)(wqkb + 12288 + 1 * 4096 + wbase);
        short8 ak2 = *(const short8*)(wqkb + 12288 + 2 * 4096 + wbase);
        accq = __builtin_amdgcn_mfma_f32_16x16x32_bf16(bm1, aq0, accq, 0, 0, 0);
        accq = __builtin_amdgcn_mfma_f32_16x16x32_bf16(b0, aq1, accq, 0, 0, 0);
        accq = __builtin_amdgcn_mfma_f32_16x16x32_bf16(bp1, aq2, accq, 0, 0, 0);
        acck = __builtin_amdgcn_mfma_f32_16x16x32_bf16(bm64, ak0, acck, 0, 0, 0);
        acck = __builtin_amdgcn_mfma_f32_16x16x32_bf16(b0, ak1, acck, 0, 0, 0);
        acck = __builtin_amdgcn_mfma_f32_16x16x32_bf16(bp64, ak2, acck, 0, 0, 0);
    }
    float4 pq, pk;
    pq.x = accq[0]; pq.y = accq[1]; pq.z = accq[2]; pq.w = accq[3];
    pk.x = acck[0]; pk.y = acck[1]; pk.z = acck[2]; pk.w = acck[3];
    redq[w][lane] = pq;
    redk[w][lane] = pk;
    __syncthreads();
    if (w == 0) {
        float4 a0 = redq[0][lane], a1 = redq[1][lane], a2 = redq[2][lane], a3 = redq[3][lane];
        float s0 = ((a0.x + a1.x) + a2.x) + a3.x;
        float s1 = ((a0.y + a1.y) + a2.y) + a3.y;
        float s2 = ((a0.z + a1.z) + a2.z) + a3.z;
        float s3 = ((a0.w + a1.w) + a2.w) + a3.w;
        float bqv = bq[c16];
        float vq0 = s0 + bqv, vq1 = s1 + bqv, vq2 = s2 + bqv, vq3 = s3 + bqv;
        ushort4 sq4;
        sq4.x = f2bf(vq0); sq4.y = f2bf(vq1); sq4.z = f2bf(vq2); sq4.w = f2bf(vq3);
        *(ushort4*)(qrawh + (size_t)(b * C16 + c16) * NN + n0 + q16 * 4) = sq4;
        float ssq = vq0 * vq0 + vq1 * vq1 + vq2 * vq2 + vq3 * vq3;
        ssq += __shfl_xor(ssq, 16, 64);
        ssq += __shfl_xor(ssq, 32, 64);
        if (lane < 16) atomicAdd(nu2 + b * C16 + lane, ssq);
    } else if (w == 1) {
        float4 a0 = redk[0][lane], a1 = redk[1][lane], a2 = redk[2][lane], a3 = redk[3][lane];
        float s0 = ((a0.x + a1.x) + a2.x) + a3.x;
        float s1 = ((a0.y + a1.y) + a2.y) + a3.y;
        float s2 = ((a0.z + a1.z) + a2.z) + a3.z;
        float s3 = ((a0.w + a1.w) + a2.w) + a3.w;
        float bkv = bk[c16];
        float vk0 = s0 + bkv, vk1 = s1 + bkv, vk2 = s2 + bkv, vk3 = s3 + bkv;
        ushort4 sk4;
        sk4.x = f2bf(vk0); sk4.y = f2bf(vk1); sk4.z = f2bf(vk2); sk4.w = f2bf(vk3);
        *(ushort4*)(krawh + (size_t)(b * C16 + c16) * NN + n0 + q16 * 4) = sk4;
        float ssk = vk0 * vk0 + vk1 * vk1 + vk2 * vk2 + vk3 * vk3;
        ssk += __shfl_xor(ssk, 16, 64);
        ssk += __shfl_xor(ssk, 32, 64);
        if (lane < 16) atomicAdd(nu2 + 64 + b * C16 + lane, ssk);
    }
}

// FRN + Mish. Mish via identity: tanh(softplus(v)) = (t^2+2t)/(t^2+2t+2), t=e^v.
__device__ __forceinline__ void frn_body(
        int blk, const unsigned short* __restrict__ qrawh, const unsigned short* __restrict__ krawh,
        const float* __restrict__ nu2, const float* __restrict__ eps_q,
        const float* __restrict__ eps_k, unsigned short* __restrict__ qb,
        unsigned short* __restrict__ kb, int tid) {
    int tensor = blk >> 8;
    int b = (blk >> 6) & 3;
    int nch = blk & 63;
    const unsigned short* raw = tensor ? krawh : qrawh;
    const float* eps = tensor ? eps_k : eps_q;
    unsigned short* outp = tensor ? kb : qb;
    const float* nu = nu2 + tensor * 64 + b * C16;
    float scale = tensor ? 1.0f : 1.44269504f;
    int n = nch * 64 + (tid & 63);
    int oq = tid >> 6;
    ushort4 pk4;
#pragma unroll
    for (int i = 0; i < 4; ++i) {
        int o = oq * 4 + i;
        float r = bf2f(raw[(size_t)(b * C16 + o) * NN + n]);
        float v = r * rsqrtf(nu[o] * (1.f / (float)NN) + fabsf(eps[o]));
        float t = EXP2(v * 1.44269504f);
        float num = t * t + 2.0f * t;
        float m = (v * num) * __builtin_amdgcn_rcpf(num + 2.0f);
        if (v > 30.f) m = v;
        m *= scale;
        ((unsigned short*)&pk4)[i] = f2bf(m);
    }
    size_t base = ((size_t)b * 128 + (n >> 5)) * 512 + (size_t)(n & 31) * 8
                + (size_t)(oq >> 1) * 256 + (oq & 1) * 4;
    *(ushort4*)(outp + base) = pk4;
}

// exp2 half-pack: 8 score elems -> one bf16 A-frag word via v_permlane32_swap_b32.
__device__ __forceinline__ void pack_half(
        const floatx16& sc, int h, short8* A, float* lsum) {
    unsigned pk[4];
    float ls = 0.f;
#pragma unroll
    for (int p = 0; p < 4; ++p) {
        float e0 = EXP2(sc[8 * h + 2 * p]);
        float e1 = EXP2(sc[8 * h + 2 * p + 1]);
        ls += e0 + e1;
        pk[p] = __builtin_amdgcn_perm(__float_as_uint(e1), __float_as_uint(e0), 0x07060302u);
    }
    *lsum += ls;
    asm("v_permlane32_swap_b32 %0, %1" : "+v"(pk[0]), "+v"(pk[2]));
    asm("v_permlane32_swap_b32 %0, %1" : "+v"(pk[1]), "+v"(pk[3]));
    union { unsigned u[4]; short8 s; } a;
    a.u[0] = pk[0]; a.u[1] = pk[1]; a.u[2] = pk[2]; a.u[3] = pk[3];
    *A = a.s;
}

// attention body: j=64 c=128 per block, split-pack interleaved (r3 structure, 49 us)
__device__ __forceinline__ void attn_body(
        int id, const unsigned short* __restrict__ qb, const unsigned short* __restrict__ kb,
        const unsigned short* __restrict__ vbuf, const float* __restrict__ x,
        const float* __restrict__ gamma_p, float* __restrict__ out,
        float (*lpart)[2][32], float (*obuf)[32][33], int tid) {
    int wv_ = __builtin_amdgcn_readfirstlane(tid >> 6);
    int lane = tid & 63;
    int l31 = lane & 31, lh = lane >> 5;
    int cs = id & 1, b = (id >> 1) & 3, jt = id >> 3;
    int jbase = jt * 64, cb = cs * 128;
    int lane8 = lane * 8;

    const unsigned short* qfb = qb + ((size_t)b * 128 + (jbase >> 5)) * 512 + lane8;
    const unsigned short* kfb = kb + ((size_t)b * 128 + (wv_ * 32)) * 512 + lane8;

    short8 qf0 = *(const short8*)qfb;
    short8 qf1 = *(const short8*)(qfb + 512);

    floatx16 z16 = {0,0,0,0,0,0,0,0,0,0,0,0,0,0,0,0};
    floatx16 acc0[4], acc1[4];
#pragma unroll
    for (int cg = 0; cg < 4; ++cg) { acc0[cg] = z16; acc1[cg] = z16; }
    float lsum0 = 0.f, lsum1 = 0.f;

    const unsigned short* vp0 = vbuf + (((size_t)b * 8 + cs * 4 + 0) * 256 + wv_ * 64) * 512 + lane8;
    const unsigned short* vp1 = vbuf + (((size_t)b * 8 + cs * 4 + 1) * 256 + wv_ * 64) * 512 + lane8;
    const unsigned short* vp2 = vbuf + (((size_t)b * 8 + cs * 4 + 2) * 256 + wv_ * 64) * 512 + lane8;
    const unsigned short* vp3 = vbuf + (((size_t)b * 8 + cs * 4 + 3) * 256 + wv_ * 64) * 512 + lane8;

    short8 ak = *(const short8*)kfb;
#pragma unroll 1
    for (int step = 0; step < 32; ++step) {
        short8 vf0a = *(const short8*)vp0;
        short8 vf1a = *(const short8*)vp1;
        short8 vf2a = *(const short8*)vp2;
        short8 vf3a = *(const short8*)vp3;
        short8 vf0b = *(const short8*)(vp0 + 512);
        short8 vf1b = *(const short8*)(vp1 + 512);
        short8 vf2b = *(const short8*)(vp2 + 512);
        short8 vf3b = *(const short8*)(vp3 + 512);
        floatx16 sc0 = __builtin_amdgcn_mfma_f32_32x32x16_bf16(ak, qf0, z16, 0, 0, 0);
        floatx16 sc1 = __builtin_amdgcn_mfma_f32_32x32x16_bf16(ak, qf1, z16, 0, 0, 0);
        ak = *(const short8*)(kfb + (size_t)((step + 1) & 31) * 512);
        short8 A;
        pack_half(sc0, 0, &A, &lsum0);                 // A00
        __builtin_amdgcn_s_setprio(1);
        acc0[0] = __builtin_amdgcn_mfma_f32_32x32x16_bf16(A, vf0a, acc0[0], 0, 0, 0);
        acc0[1] = __builtin_amdgcn_mfma_f32_32x32x16_bf16(A, vf1a, acc0[1], 0, 0, 0);
        acc0[2] = __builtin_amdgcn_mfma_f32_32x32x16_bf16(A, vf2a, acc0[2], 0, 0, 0);
        acc0[3] = __builtin_amdgcn_mfma_f32_32x32x16_bf16(A, vf3a, acc0[3], 0, 0, 0);
        __builtin_amdgcn_s_setprio(0);
        __builtin_amdgcn_sched_barrier(0);
        pack_half(sc0, 1, &A, &lsum0);                 // A01
        __builtin_amdgcn_s_setprio(1);
        acc0[0] = __builtin_amdgcn_mfma_f32_32x32x16_bf16(A, vf0b, acc0[0], 0, 0, 0);
        acc0[1] = __builtin_amdgcn_mfma_f32_32x32x16_bf16(A, vf1b, acc0[1], 0, 0, 0);
        acc0[2] = __builtin_amdgcn_mfma_f32_32x32x16_bf16(A, vf2b, acc0[2], 0, 0, 0);
        acc0[3] = __builtin_amdgcn_mfma_f32_32x32x16_bf16(A, vf3b, acc0[3], 0, 0, 0);
        __builtin_amdgcn_s_setprio(0);
        __builtin_amdgcn_sched_barrier(0);
        pack_half(sc1, 0, &A, &lsum1);                 // A10
        __builtin_amdgcn_s_setprio(1);
        acc1[0] = __builtin_amdgcn_mfma_f32_32x32x16_bf16(A, vf0a, acc1[0], 0, 0, 0);
        acc1[1] = __builtin_amdgcn_mfma_f32_32x32x16_bf16(A, vf1a, acc1[1], 0, 0, 0);
        acc1[2] = __builtin_amdgcn_mfma_f32_32x32x16_bf16(A, vf2a, acc1[2], 0, 0, 0);
        acc1[3] = __builtin_amdgcn_mfma_f32_32x32x16_bf16(A, vf3a, acc1[3], 0, 0, 0);
        __builtin_amdgcn_s_setprio(0);
        __builtin_amdgcn_sched_barrier(0);
        pack_half(sc1, 1, &A, &lsum1);                 // A11
        __builtin_amdgcn_s_setprio(1);
        acc1[0] = __builtin_amdgcn_mfma_f32_32x32x16_bf16(A, vf0b, acc1[0], 0, 0, 0);
        acc1[1] = __builtin_amdgcn_mfma_f32_32x32x16_bf16(A, vf1b, acc1[1], 0, 0, 0);
        acc1[2] = __builtin_amdgcn_mfma_f32_32x32x16_bf16(A, vf2b, acc1[2], 0, 0, 0);
        acc1[3] = __builtin_amdgcn_mfma_f32_32x32x16_bf16(A, vf3b, acc1[3], 0, 0, 0);
        __builtin_amdgcn_s_setprio(0);
        vp0 += 1024; vp1 += 1024; vp2 += 1024; vp3 += 1024;
    }

    lsum0 += __shfl_xor(lsum0, 32, 64);
    lsum1 += __shfl_xor(lsum1, 32, 64);
    if (lh == 0) { lpart[wv_][0][l31] = lsum0; lpart[wv_][1][l31] = lsum1; }
    __syncthreads();

    int j31 = tid & 31;
    float gamma = gamma_p[0];
    float gl0 = gamma / (lpart[0][0][j31] + lpart[1][0][j31] + lpart[2][0][j31] + lpart[3][0][j31]);
    float gl1 = gamma / (lpart[0][1][j31] + lpart[1][1][j31] + lpart[2][1][j31] + lpart[3][1][j31]);
    const float* xbb = x + (size_t)b * CC * NN;
    float* obb = out + (size_t)b * CC * NN;
    int hofs = lh * 4;
    int cgrp = tid >> 5;
#pragma unroll
    for (int jg = 0; jg < 2; ++jg) {
        float gl = jg ? gl1 : gl0;
#pragma unroll
        for (int cg = 0; cg < 4; ++cg) {
            __syncthreads();
            const floatx16& a = jg ? acc1[cg] : acc0[cg];
#pragma unroll
            for (int r = 0; r < 16; ++r) {
                int row = (r & 3) + 8 * (r >> 2) + hofs;
                obuf[wv_][row][l31] = a[r];
            }
            __syncthreads();
#pragma unroll
            for (int i = 0; i < 4; ++i) {
                int c = cgrp * 4 + i;
                float val = obuf[0][j31][c] + obuf[1][j31][c] + obuf[2][j31][c] + obuf[3][j31][c];
                size_t oidx = (size_t)(cb + cg * 32 + c) * NN + jbase + jg * 32 + j31;
                obb[oidx] = fmaf(gl, val, xbb[oidx]);
            }
        }
    }
}

// ================= kernels ==========
__global__ __launch_bounds__(256) void prep_kernel(
        const float* __restrict__ x, const float* __restrict__ wv,
        const float* __restrict__ wq, const float* __restrict__ wk,
        unsigned short* __restrict__ xT, unsigned short* __restrict__ wvb,
        unsigned short* __restrict__ wqkb, float* __restrict__ nu2) {
    __shared__ float tile_t[64][65];
    int bid = blockIdx.x;
    if (bid < 1024) prep_tile_body(bid, x, xT, tile_t, threadIdx.x);
    else prep_wt_body(bid, wv, wq, wk, wvb, wqkb, nu2, threadIdx.x);
}

// grid 1536: blocks 0..511 conv_v, 512..1535 conv_qk (1024 units).
__global__ __launch_bounds__(256) void conv_kernel(
        const unsigned short* __restrict__ xT, const unsigned short* __restrict__ wvb,
        const unsigned short* __restrict__ wqkb, const float* __restrict__ bv,
        const float* __restrict__ bq, const float* __restrict__ bk,
        unsigned short* __restrict__ vbuf, unsigned short* __restrict__ qrawh,
        unsigned short* __restrict__ krawh, float* __restrict__ nu2) {
    __shared__ float4 redq[4][64];
    __shared__ float4 redk[4][64];
    int bid = blockIdx.x;
    if (bid < 512) conv_v_body(bid, xT, wvb, bv, vbuf, threadIdx.x);
    else conv_qk_body_v2(bid - 512, xT, wqkb, bq, bk, qrawh, krawh, nu2,
                         threadIdx.x, redq, redk);
}

__global__ __launch_bounds__(256) void frn_mish_kernel(
        const unsigned short* __restrict__ qrawh, const unsigned short* __restrict__ krawh,
        const float* __restrict__ nu2, const float* __restrict__ eps_q,
        const float* __restrict__ eps_k, unsigned short* __restrict__ qb,
        unsigned short* __restrict__ kb) {
    frn_body(blockIdx.x, qrawh, krawh, nu2, eps_q, eps_k, qb, kb, threadIdx.x);
}

__global__ __launch_bounds__(256, 2) void attn_kernel(
        const unsigned short* __restrict__ qb, const unsigned short* __restrict__ kb,
        const unsigned short* __restrict__ vbuf, const float* __restrict__ x,
        const float* __restrict__ gamma_p, float* __restrict__ out) {
    __shared__ float lpart[4][2][32];
    __shared__ float obuf[4][32][33];
    attn_body(blockIdx.x, qb, kb, vbuf, x, gamma_p, out, lpart, obuf, threadIdx.x);
}

extern "C" void kernel_launch(void* const* d_in, const int* in_sizes, int n_in,
                              void* d_out, int out_size, void* d_ws, size_t ws_size,
                              hipStream_t stream) {
    const float* x     = (const float*)d_in[0];
    const float* wq    = (const float*)d_in[1];
    const float* bq    = (const float*)d_in[2];
    const float* wk    = (const float*)d_in[3];
    const float* bk    = (const float*)d_in[4];
    const float* wv    = (const float*)d_in[5];
    const float* bv    = (const float*)d_in[6];
    const float* gamma = (const float*)d_in[7];
    const float* eps_q = (const float*)d_in[8];
    const float* eps_k = (const float*)d_in[9];
    float* out = (float*)d_out;
    char* ws = (char*)d_ws;

    unsigned short* qrawh = (unsigned short*)ws;
    unsigned short* krawh = (unsigned short*)(ws + (1u << 20));
    float* nu2  = (float*)(ws + (2u << 20));
    unsigned short* qb = (unsigned short*)(ws + (2u << 20) + 4096);
    unsigned short* kb = qb + (size_t)NB * NN * C16;
    unsigned short* vbuf = kb + (size_t)NB * NN * C16;
    unsigned short* xT = vbuf + (size_t)NB * CC * NN;
    unsigned short* wvb = xT + (size_t)NB * NN * CC;
    unsigned short* wqkb = wvb + (size_t)CC * CC;

    prep_kernel<<<dim3(1112), dim3(256), 0, stream>>>(x, wv, wq, wk, xT, wvb, wqkb, nu2);
    conv_kernel<<<dim3(1536), dim3(256), 0, stream>>>(xT, wvb, wqkb, bv, bq, bk, vbuf, qrawh, krawh, nu2);
    frn_mish_kernel<<<dim3(512), dim3(256), 0, stream>>>(qrawh, krawh, nu2, eps_q, eps_k, qb, kb);
    attn_kernel<<<dim3(512), dim3(256), 0, stream>>>(qb, kb, vbuf, x, gamma, out);
}